// Round 1
// baseline (264.261 us; speedup 1.0000x reference)
//
#include <hip/hip_runtime.h>

// LSTM: B=16384 independent sequences, T=512, I=4, H=4, then FC 4->1.
// Strategy: 4 lanes per sequence (one per hidden unit j). 65536 threads =
// 1024 waves = 1 wave per SIMD on all 256 CUs. h exchanged within the
// aligned 4-lane quad via DPP quad_perm (no LDS). W_hh columns are loaded
// pre-permuted per-lane so term m multiplies h from lane j^m.

#define CH 8  // time-chunk for double-buffered X prefetch

__device__ __forceinline__ float fast_sigmoid(float x) {
    float e = __builtin_amdgcn_exp2f(-1.44269504f * x);   // exp(-x)
    return __builtin_amdgcn_rcpf(1.0f + e);
}

__device__ __forceinline__ float fast_tanh(float x) {
    // tanh(x) = 2*sigmoid(2x) - 1
    float e = __builtin_amdgcn_exp2f(-2.88539008f * x);
    float r = __builtin_amdgcn_rcpf(1.0f + e);
    return fmaf(2.0f, r, -1.0f);
}

// DPP quad_perm lane xor within aligned quads: xor1=0xB1, xor2=0x4E, xor3=0x1B
template <int CTRL>
__device__ __forceinline__ float quad_xor(float v) {
    int i = __float_as_int(v);
    int r = __builtin_amdgcn_mov_dpp(i, CTRL, 0xF, 0xF, true);
    return __int_as_float(r);
}

__global__ __launch_bounds__(256) void lstm_h4_kernel(
    const float* __restrict__ X,
    const float* __restrict__ W_ih,
    const float* __restrict__ W_hh,
    const float* __restrict__ b_ih,
    const float* __restrict__ b_hh,
    const float* __restrict__ W_fc,
    const float* __restrict__ b_fc,
    float* __restrict__ out,
    int B, int T)
{
    int gid = blockIdx.x * blockDim.x + threadIdx.x;
    int b = gid >> 2;       // sequence index
    int j = gid & 3;        // hidden unit index
    if (b >= B) return;

    // Per-lane weights. Gate order (PyTorch): rows 0-3=i, 4-7=f, 8-11=g, 12-15=o.
    // This lane owns rows {j, 4+j, 8+j, 12+j}.
    // whh[g][m] multiplies h obtained from lane j^m -> store W_hh[row][j^m].
    float wih[4][4], whh[4][4], bias[4];
#pragma unroll
    for (int g = 0; g < 4; ++g) {
        int row = g * 4 + j;
#pragma unroll
        for (int k = 0; k < 4; ++k) {
            wih[g][k] = W_ih[row * 4 + k];
            whh[g][k] = W_hh[row * 4 + (j ^ k)];
        }
        bias[g] = b_ih[row] + b_hh[row];
    }

    const float4* __restrict__ xp = (const float4*)X + (size_t)b * T;

    float h = 0.0f, c = 0.0f;

    float4 cur[CH], nxt[CH];
#pragma unroll
    for (int i = 0; i < CH; ++i) cur[i] = xp[i];

    for (int tc = 0; tc < T; tc += CH) {
        if (tc + CH < T) {
#pragma unroll
            for (int i = 0; i < CH; ++i) nxt[i] = xp[tc + CH + i];
        }
#pragma unroll
        for (int i = 0; i < CH; ++i) {
            float4 x = cur[i];
            float h1 = quad_xor<0xB1>(h);   // h from lane j^1
            float h2 = quad_xor<0x4E>(h);   // h from lane j^2
            float h3 = quad_xor<0x1B>(h);   // h from lane j^3
            float pre[4];
#pragma unroll
            for (int g = 0; g < 4; ++g) {
                float p = bias[g];
                p = fmaf(wih[g][0], x.x, p);
                p = fmaf(wih[g][1], x.y, p);
                p = fmaf(wih[g][2], x.z, p);
                p = fmaf(wih[g][3], x.w, p);
                p = fmaf(whh[g][0], h,  p);
                p = fmaf(whh[g][1], h1, p);
                p = fmaf(whh[g][2], h2, p);
                p = fmaf(whh[g][3], h3, p);
                pre[g] = p;
            }
            float ig = fast_sigmoid(pre[0]);
            float fg = fast_sigmoid(pre[1]);
            float gg = fast_tanh(pre[2]);
            float og = fast_sigmoid(pre[3]);
            c = fmaf(fg, c, ig * gg);
            h = og * fast_tanh(c);
        }
#pragma unroll
        for (int i = 0; i < CH; ++i) cur[i] = nxt[i];
    }

    // out[b] = sum_j h_j * W_fc[j] + b_fc  (reduce across the quad)
    float partial = h * W_fc[j];
    partial += quad_xor<0xB1>(partial);
    partial += quad_xor<0x4E>(partial);
    if (j == 0) out[b] = partial + b_fc[0];
}

extern "C" void kernel_launch(void* const* d_in, const int* in_sizes, int n_in,
                              void* d_out, int out_size, void* d_ws, size_t ws_size,
                              hipStream_t stream) {
    const float* X    = (const float*)d_in[0];
    const float* W_ih = (const float*)d_in[1];
    const float* W_hh = (const float*)d_in[2];
    const float* b_ih = (const float*)d_in[3];
    const float* b_hh = (const float*)d_in[4];
    const float* W_fc = (const float*)d_in[5];
    const float* b_fc = (const float*)d_in[6];
    float* out = (float*)d_out;

    int B = out_size;                       // 16384
    int T = in_sizes[0] / (B * 4);          // 512 (I=4)

    int threads = B * 4;
    dim3 block(256);
    dim3 grid((threads + 255) / 256);
    lstm_h4_kernel<<<grid, block, 0, stream>>>(X, W_ih, W_hh, b_ih, b_hh,
                                               W_fc, b_fc, out, B, T);
}

// Round 2
// 250.858 us; speedup vs baseline: 1.0534x; 1.0534x over previous
//
#include <hip/hip_runtime.h>

// LSTM: B=16384 independent sequences, T=512, I=4, H=4, then FC 4->1.
// 4 lanes per sequence (one per hidden unit j); 1024 waves = 1 wave/SIMD.
// Round 2: pack gate pairs (i,f) and (g,o) into float2 -> v_pk_fma_f32 /
// v_pk_mul_f32 halve issue count and dep-chain depth; W_ih*x+bias computed
// per-step from prefetched x, independent of the h/c recurrence, giving the
// scheduler slack work to fill transcendental-latency stalls.

#define CH 8  // time-chunk for double-buffered X prefetch

typedef float v2f __attribute__((ext_vector_type(2)));

__device__ __forceinline__ v2f pk_fma(v2f a, v2f b, v2f c) {
    return __builtin_elementwise_fma(a, b, c);
}

__device__ __forceinline__ float fast_tanh(float x) {
    // tanh(x) = 2*sigmoid(2x) - 1 = 2/(1+exp(-2x)) - 1
    float e = __builtin_amdgcn_exp2f(-2.88539008f * x);
    float r = __builtin_amdgcn_rcpf(1.0f + e);
    return fmaf(2.0f, r, -1.0f);
}

// DPP quad_perm lane xor within aligned quads: xor1=0xB1, xor2=0x4E, xor3=0x1B
template <int CTRL>
__device__ __forceinline__ float quad_xor(float v) {
    int i = __float_as_int(v);
    int r = __builtin_amdgcn_mov_dpp(i, CTRL, 0xF, 0xF, true);
    return __int_as_float(r);
}

__global__ __launch_bounds__(256) void lstm_h4_kernel(
    const float* __restrict__ X,
    const float* __restrict__ W_ih,
    const float* __restrict__ W_hh,
    const float* __restrict__ b_ih,
    const float* __restrict__ b_hh,
    const float* __restrict__ W_fc,
    const float* __restrict__ b_fc,
    float* __restrict__ out,
    int B, int T)
{
    int gid = blockIdx.x * blockDim.x + threadIdx.x;
    int b = gid >> 2;       // sequence index
    int j = gid & 3;        // hidden unit index
    if (b >= B) return;

    // Gate order (PyTorch rows): 0-3=i, 4-7=f, 8-11=g, 12-15=o.
    // Pair 0 = (i_j, f_j) rows (j, 4+j); pair 1 = (g_j, o_j) rows (8+j, 12+j).
    // whh_*[k] multiplies h obtained from lane j^k -> column (j^k).
    v2f wih0[4], wih1[4], whh0[4], whh1[4], bias0, bias1;
    {
        int rI = 0 * 4 + j, rF = 1 * 4 + j, rG = 2 * 4 + j, rO = 3 * 4 + j;
#pragma unroll
        for (int k = 0; k < 4; ++k) {
            wih0[k] = (v2f){W_ih[rI * 4 + k], W_ih[rF * 4 + k]};
            wih1[k] = (v2f){W_ih[rG * 4 + k], W_ih[rO * 4 + k]};
            int kc = j ^ k;
            whh0[k] = (v2f){W_hh[rI * 4 + kc], W_hh[rF * 4 + kc]};
            whh1[k] = (v2f){W_hh[rG * 4 + kc], W_hh[rO * 4 + kc]};
        }
        bias0 = (v2f){b_ih[rI] + b_hh[rI], b_ih[rF] + b_hh[rF]};
        bias1 = (v2f){b_ih[rG] + b_hh[rG], b_ih[rO] + b_hh[rO]};
    }

    // Nonlinearity constants, packed per pair:
    //   y = s * rcp(1 + exp2(m*x)) + t
    //   sigmoid: m=-1.4427, s=1, t=0;  tanh: m=-2.8854, s=2, t=-1
    const v2f m_if = (v2f){-1.44269504f, -1.44269504f};
    const v2f m_go = (v2f){-2.88539008f, -1.44269504f};   // (tanh, sigmoid)
    const v2f s_go = (v2f){2.0f, 1.0f};
    const v2f t_go = (v2f){-1.0f, 0.0f};

    const float4* __restrict__ xp = (const float4*)X + (size_t)b * T;

    float h = 0.0f, c = 0.0f;

    float4 cur[CH], nxt[CH];
#pragma unroll
    for (int i = 0; i < CH; ++i) cur[i] = xp[i];

    for (int tc = 0; tc < T; tc += CH) {
        if (tc + CH < T) {
#pragma unroll
            for (int i = 0; i < CH; ++i) nxt[i] = xp[tc + CH + i];
        }
#pragma unroll
        for (int i = 0; i < CH; ++i) {
            float4 x = cur[i];
            // ---- x path: independent of recurrence (scheduler slack) ----
            v2f p0 = bias0, p1 = bias1;
            p0 = pk_fma(wih0[0], (v2f){x.x, x.x}, p0);
            p1 = pk_fma(wih1[0], (v2f){x.x, x.x}, p1);
            p0 = pk_fma(wih0[1], (v2f){x.y, x.y}, p0);
            p1 = pk_fma(wih1[1], (v2f){x.y, x.y}, p1);
            p0 = pk_fma(wih0[2], (v2f){x.z, x.z}, p0);
            p1 = pk_fma(wih1[2], (v2f){x.z, x.z}, p1);
            p0 = pk_fma(wih0[3], (v2f){x.w, x.w}, p0);
            p1 = pk_fma(wih1[3], (v2f){x.w, x.w}, p1);

            // ---- recurrence path ----
            float h1 = quad_xor<0xB1>(h);
            float h2 = quad_xor<0x4E>(h);
            float h3 = quad_xor<0x1B>(h);
            v2f hb0 = (v2f){h,  h};
            v2f hb1 = (v2f){h1, h1};
            v2f hb2 = (v2f){h2, h2};
            v2f hb3 = (v2f){h3, h3};
            p0 = pk_fma(whh0[0], hb0, p0);
            p1 = pk_fma(whh1[0], hb0, p1);
            p0 = pk_fma(whh0[1], hb1, p0);
            p1 = pk_fma(whh1[1], hb1, p1);
            p0 = pk_fma(whh0[2], hb2, p0);
            p1 = pk_fma(whh1[2], hb2, p1);
            p0 = pk_fma(whh0[3], hb3, p0);
            p1 = pk_fma(whh1[3], hb3, p1);

            // ---- nonlinearities (packed pre/post, scalar exp/rcp) ----
            v2f a_if = p0 * m_if;
            v2f a_go = p1 * m_go;
            v2f e_if = (v2f){__builtin_amdgcn_exp2f(a_if.x),
                             __builtin_amdgcn_exp2f(a_if.y)};
            v2f e_go = (v2f){__builtin_amdgcn_exp2f(a_go.x),
                             __builtin_amdgcn_exp2f(a_go.y)};
            v2f d_if = e_if + (v2f){1.0f, 1.0f};
            v2f d_go = e_go + (v2f){1.0f, 1.0f};
            float ig = __builtin_amdgcn_rcpf(d_if.x);
            float fg = __builtin_amdgcn_rcpf(d_if.y);
            v2f r_go = (v2f){__builtin_amdgcn_rcpf(d_go.x),
                             __builtin_amdgcn_rcpf(d_go.y)};
            v2f go = pk_fma(s_go, r_go, t_go);   // (tanh g, sigmoid o)

            c = fmaf(fg, c, ig * go.x);
            h = go.y * fast_tanh(c);
        }
#pragma unroll
        for (int i = 0; i < CH; ++i) cur[i] = nxt[i];
    }

    // out[b] = sum_j h_j * W_fc[j] + b_fc  (reduce across the quad)
    float partial = h * W_fc[j];
    partial += quad_xor<0xB1>(partial);
    partial += quad_xor<0x4E>(partial);
    if (j == 0) out[b] = partial + b_fc[0];
}

extern "C" void kernel_launch(void* const* d_in, const int* in_sizes, int n_in,
                              void* d_out, int out_size, void* d_ws, size_t ws_size,
                              hipStream_t stream) {
    const float* X    = (const float*)d_in[0];
    const float* W_ih = (const float*)d_in[1];
    const float* W_hh = (const float*)d_in[2];
    const float* b_ih = (const float*)d_in[3];
    const float* b_hh = (const float*)d_in[4];
    const float* W_fc = (const float*)d_in[5];
    const float* b_fc = (const float*)d_in[6];
    float* out = (float*)d_out;

    int B = out_size;                       // 16384
    int T = in_sizes[0] / (B * 4);          // 512 (I=4)

    int threads = B * 4;
    dim3 block(256);
    dim3 grid((threads + 255) / 256);
    lstm_h4_kernel<<<grid, block, 0, stream>>>(X, W_ih, W_hh, b_ih, b_hh,
                                               W_fc, b_fc, out, B, T);
}